// Round 2
// baseline (301.305 us; speedup 1.0000x reference)
//
#include <hip/hip_runtime.h>
#include <stdint.h>

#define B 32
#define P 24564
#define NCLS 21
#define NOBJ 24
#define THRESH 0.5f
#define SCHUNK 16
#define CHUNK 1536     // ceil(24564/16) for k_objmax
#define NCHUNK 96      // ceil(24564/256) for k_main
#define NBKT 2048      // 11-bit histogram buckets (bits [30:20])
#define CAP 4000       // compact boundary-list capacity per batch

// ws layout (bytes) — total 3,925,152 (<= 3.93 MB known-safe)
#define OFF_ACC     0        // double[3]: loc_sum, conf_pos, conf_neg
#define OFF_NPOS    32       // int[B]
#define OFF_META    160      // int4[B]: {b0, Kp, cnt, pad}
#define OFF_OBJBEST 672      // ull[B*NOBJ] = 6144
#define OFF_HIST    6816     // u32[B*NBKT] = 262144
#define INIT_BYTES  268960
#define OFF_CENEG   268960   // float[B*P] = 3144192
#define OFF_LIST    3413152  // u32[B*CAP] = 512000

__device__ __forceinline__ unsigned long long umax64(unsigned long long a, unsigned long long b) {
    return a > b ? a : b;
}

// ---------------- Kernel 1: per-object best prior (argmax over p, first-index tie) ----------
__global__ __launch_bounds__(256) void k_objmax(
    const float* __restrict__ gt_boxes, const float* __restrict__ anchor,
    unsigned long long* __restrict__ obj_best) {
#pragma clang fp contract(off)
    int b = blockIdx.y;
    int p0 = blockIdx.x * CHUNK;
    int p1 = min(P, p0 + CHUNK);
    int tid = threadIdx.x;
    __shared__ float4 sbox[NOBJ];
    __shared__ unsigned long long sbest[NOBJ];
    if (tid < NOBJ) {
        const float* g = gt_boxes + (size_t)(b * NOBJ + tid) * 4;
        sbox[tid] = make_float4(g[0], g[1], g[2], g[3]);
        sbest[tid] = 0ull;
    }
    __syncthreads();
    unsigned long long best[NOBJ];
#pragma unroll
    for (int n = 0; n < NOBJ; n++) best[n] = 0ull;

    for (int p = p0 + tid; p < p1; p += 256) {
        const float* a = anchor + (size_t)p * 4;
        float acx = a[0], acy = a[1], aw = a[2], ah = a[3];
        float ax0 = acx - aw * 0.5f, ay0 = acy - ah * 0.5f;
        float ax1 = acx + aw * 0.5f, ay1 = acy + ah * 0.5f;
        float area_a = (ax1 - ax0) * (ay1 - ay0);
        unsigned long long pk = (unsigned long long)(~(unsigned)p);
#pragma unroll
        for (int n = 0; n < NOBJ; n++) {
            float4 bx = sbox[n];
            float ltx = fmaxf(bx.x, ax0), lty = fmaxf(bx.y, ay0);
            float rbx = fminf(bx.z, ax1), rby = fminf(bx.w, ay1);
            float w = fmaxf(rbx - ltx, 0.f), h = fmaxf(rby - lty, 0.f);
            float inter = w * h;
            float area_o = (bx.z - bx.x) * (bx.w - bx.y);
            float iou = inter / (area_o + area_a - inter);
            unsigned long long key = ((unsigned long long)__float_as_uint(iou) << 32) | pk;
            best[n] = umax64(best[n], key);
        }
    }
#pragma unroll
    for (int n = 0; n < NOBJ; n++) {
        unsigned long long v = best[n];
        for (int off = 32; off > 0; off >>= 1)
            v = umax64(v, __shfl_down(v, off, 64));
        if ((tid & 63) == 0) atomicMax(&sbest[n], v);
    }
    __syncthreads();
    if (tid < NOBJ) atomicMax(&obj_best[b * NOBJ + tid], sbest[tid]);
}

// ---------------- Kernel 2: fused match + loc-L1 + CE + histogram ----------------------------
__global__ __launch_bounds__(256) void k_main(
    const float* __restrict__ pred_cls, const float* __restrict__ pred_loc,
    const float* __restrict__ gt_boxes, const int* __restrict__ gt_labels,
    const float* __restrict__ anchor, const unsigned long long* __restrict__ obj_best,
    float* __restrict__ ce_neg, unsigned* __restrict__ hist,
    int* __restrict__ n_pos, double* __restrict__ acc) {
#pragma clang fp contract(off)
    __shared__ float4 sbox[NOBJ];
    __shared__ int slab[NOBJ];
    __shared__ int sobj[NOBJ];
    __shared__ __align__(16) float sx[256 * NCLS];
    __shared__ unsigned shist[NBKT];
    __shared__ float swl[4];
    __shared__ float swc[4];
    __shared__ int swn[4];
    int b = blockIdx.y;
    int p0 = blockIdx.x * 256;
    int nelem = min(256, P - p0);
    int tid = threadIdx.x;

    for (int i = tid; i < NBKT; i += 256) shist[i] = 0u;
    if (tid < NOBJ) {
        const float* g = gt_boxes + (size_t)(b * NOBJ + tid) * 4;
        sbox[tid] = make_float4(g[0], g[1], g[2], g[3]);
        slab[tid] = gt_labels[b * NOBJ + tid];
        sobj[tid] = (int)(~(unsigned)(obj_best[b * NOBJ + tid] & 0xFFFFFFFFull));
    }
    // stage pred_cls chunk into LDS (16B-aligned: (b*P + p0)*21*4 is /16)
    const float* gbase = pred_cls + ((size_t)b * P + p0) * NCLS;
    int nflt = nelem * NCLS;
    int nf4 = nflt >> 2;
    const float4* g4 = (const float4*)gbase;
    for (int i = tid; i < nf4; i += 256) ((float4*)sx)[i] = g4[i];
    for (int i = (nf4 << 2) + tid; i < nflt; i += 256) sx[i] = gbase[i];
    __syncthreads();

    float lsum = 0.f, cp = 0.f;
    int lnp = 0;
    if (tid < nelem) {
        int p = p0 + tid;
        const float* a = anchor + (size_t)p * 4;
        float acx = a[0], acy = a[1], aw = a[2], ah = a[3];
        float ax0 = acx - aw * 0.5f, ay0 = acy - ah * 0.5f;
        float ax1 = acx + aw * 0.5f, ay1 = acy + ah * 0.5f;
        float area_a = (ax1 - ax0) * (ay1 - ay0);
        float bv = -1.f;
        int bn = 0;
#pragma unroll
        for (int n = 0; n < NOBJ; n++) {
            float4 bx = sbox[n];
            float ltx = fmaxf(bx.x, ax0), lty = fmaxf(bx.y, ay0);
            float rbx = fminf(bx.z, ax1), rby = fminf(bx.w, ay1);
            float w = fmaxf(rbx - ltx, 0.f), h = fmaxf(rby - lty, 0.f);
            float inter = w * h;
            float area_o = (bx.z - bx.x) * (bx.w - bx.y);
            float iou = inter / (area_o + area_a - inter);
            if (p == sobj[n]) iou = 1.0f;
            if (iou > bv) { bv = iou; bn = n; }
        }
        int pos = (bv >= THRESH) ? 1 : 0;
        int cls = pos ? (slab[bn] + 1) : 0;
        // cross entropy from LDS row
        const float* x = sx + tid * NCLS;
        float m = x[0];
#pragma unroll
        for (int j = 1; j < NCLS; j++) m = fmaxf(m, x[j]);
        float s = 0.f;
#pragma unroll
        for (int j = 0; j < NCLS; j++) s += expf(x[j] - m);
        float ce = m + logf(s) - x[cls];
        size_t idx = (size_t)b * P + p;
        if (pos) {
            lnp = 1;
            cp = ce;
            ce_neg[idx] = 0.f;
            float4 bx = sbox[bn];
            float bcx = (bx.x + bx.z) * 0.5f, bcy = (bx.y + bx.w) * 0.5f;
            float bw = bx.z - bx.x, bh = bx.w - bx.y;
            float t0 = (bcx - acx) / (aw / 10.0f);
            float t1 = (bcy - acy) / (ah / 10.0f);
            float t2 = logf(bw / aw) * 5.0f;
            float t3 = logf(bh / ah) * 5.0f;
            float4 pl = *(const float4*)(pred_loc + idx * 4);
            lsum = fabsf(pl.x - t0) + fabsf(pl.y - t1) + fabsf(pl.z - t2) + fabsf(pl.w - t3);
        } else {
            ce_neg[idx] = ce;
            atomicAdd(&shist[__float_as_uint(ce) >> 20], 1u);
        }
    }
    for (int off = 32; off > 0; off >>= 1) {
        lsum += __shfl_down(lsum, off, 64);
        cp   += __shfl_down(cp, off, 64);
        lnp  += __shfl_down(lnp, off, 64);
    }
    if ((tid & 63) == 0) { swl[tid >> 6] = lsum; swc[tid >> 6] = cp; swn[tid >> 6] = lnp; }
    __syncthreads();
    // flush histogram
    for (int i = tid; i < NBKT; i += 256) {
        unsigned c = shist[i];
        if (c) atomicAdd(&hist[b * NBKT + i], c);
    }
    if (tid == 0) {
        float ls = swl[0] + swl[1] + swl[2] + swl[3];
        float cs = swc[0] + swc[1] + swc[2] + swc[3];
        int np = swn[0] + swn[1] + swn[2] + swn[3];
        if (np) atomicAdd(&n_pos[b], np);
        atomicAdd(&acc[0], (double)ls);
        atomicAdd(&acc[1], (double)cs);
    }
}

// ---------------- Kernel 3: find boundary bucket per batch -----------------------------------
__global__ __launch_bounds__(256) void k_sel2(
    const unsigned* __restrict__ hist, const int* __restrict__ n_pos,
    int4* __restrict__ meta) {
    int b = blockIdx.x;
    int tid = threadIdx.x;
    __shared__ unsigned part[256];
    __shared__ unsigned sh[NBKT];
    const unsigned* h = hist + b * NBKT;
    unsigned s = 0;
#pragma unroll
    for (int j = 0; j < NBKT / 256; j++) {
        unsigned v = h[tid * (NBKT / 256) + j];
        sh[tid * (NBKT / 256) + j] = v;
        s += v;
    }
    part[tid] = s;
    __syncthreads();
    if (tid == 0) {
        int K = n_pos[b] * 3;
        if (K > P) K = P;
        int b0 = NBKT, Kp = 0;
        if (K > 0) {
            unsigned c = 0;
            int seg = 255;
            for (; seg >= 0; seg--) {
                if (c + part[seg] >= (unsigned)K) break;
                c += part[seg];
            }
            if (seg < 0) {
                // total negatives < K: boundary is bucket 0, zero-padding handled downstream
                b0 = 0;
                Kp = K - (int)(c - sh[0]);
            } else {
                int i = seg * (NBKT / 256) + (NBKT / 256) - 1;
                for (;; i--) {
                    if (c + sh[i] >= (unsigned)K) break;
                    c += sh[i];
                }
                b0 = i;
                Kp = K - (int)c;
            }
        }
        meta[b] = make_int4(b0, Kp, 0, 0);
    }
}

// ---------------- Kernel 4: sum above boundary, compact boundary elements --------------------
#define S3CHUNK 2048
__global__ __launch_bounds__(256) void k_sel3(
    const float* __restrict__ ce_neg, int4* __restrict__ meta,
    unsigned* __restrict__ list, double* __restrict__ acc) {
    int b = blockIdx.y;
    int tid = threadIdx.x;
    int b0 = meta[b].x;
    int* cntp = &((int*)meta)[b * 4 + 2];
    int i0 = blockIdx.x * S3CHUNK;
    int i1 = min(P, i0 + S3CHUNK);
    const uint4* x4 = (const uint4*)(ce_neg + (size_t)b * P) + (i0 >> 2);
    int n4 = (i1 - i0) >> 2;
    __shared__ double sds[4];
    double s = 0.0;
    for (int i = tid; i < n4; i += 256) {
        uint4 v = x4[i];
        unsigned vv[4] = {v.x, v.y, v.z, v.w};
#pragma unroll
        for (int j = 0; j < 4; j++) {
            int bk = (int)(vv[j] >> 20);
            if (bk > b0) {
                s += (double)__uint_as_float(vv[j]);
            } else if (bk == b0) {
                int pos = atomicAdd(cntp, 1);
                if (pos < CAP) list[b * CAP + pos] = vv[j];
            }
        }
    }
    for (int off = 32; off > 0; off >>= 1) s += __shfl_down(s, off, 64);
    if ((tid & 63) == 0) sds[tid >> 6] = s;
    __syncthreads();
    if (tid == 0) {
        double t = sds[0] + sds[1] + sds[2] + sds[3];
        if (t != 0.0) atomicAdd(&acc[2], t);
    }
}

// ---------------- Kernel 5: exact top-K' within boundary bucket ------------------------------
__global__ __launch_bounds__(256) void k_sel4(
    const float* __restrict__ ce_neg, const int4* __restrict__ meta,
    const unsigned* __restrict__ list, double* __restrict__ acc) {
    int b = blockIdx.x;
    int tid = threadIdx.x;
    int4 m = meta[b];
    int b0 = m.x, Kp = m.y, cnt = m.z;
    if (Kp <= 0) return;
    __shared__ int sci[4];
    __shared__ double sds[4];
    bool useList = (cnt <= CAP);
    const unsigned* src = useList ? (list + b * CAP) : (const unsigned*)(ce_neg + (size_t)b * P);
    int n = useList ? cnt : P;

    unsigned T = 0;
    for (int bit = 30; bit >= 0; bit--) {
        unsigned cand = T | (1u << bit);
        int c = 0;
        for (int i = tid; i < n; i += 256) {
            unsigned v = src[i];
            if (!useList && (int)(v >> 20) != b0) continue;
            c += (v >= cand) ? 1 : 0;
        }
        for (int off = 32; off > 0; off >>= 1) c += __shfl_down(c, off, 64);
        if ((tid & 63) == 0) sci[tid >> 6] = c;
        __syncthreads();
        int total = sci[0] + sci[1] + sci[2] + sci[3];
        __syncthreads();
        if (total >= Kp) T = cand;
    }
    int cgt = 0;
    double s = 0.0;
    for (int i = tid; i < n; i += 256) {
        unsigned v = src[i];
        if (!useList && (int)(v >> 20) != b0) continue;
        if (v > T) { cgt++; s += (double)__uint_as_float(v); }
    }
    for (int off = 32; off > 0; off >>= 1) {
        cgt += __shfl_down(cgt, off, 64);
        s   += __shfl_down(s, off, 64);
    }
    if ((tid & 63) == 0) { sci[tid >> 6] = cgt; sds[tid >> 6] = s; }
    __syncthreads();
    if (tid == 0) {
        int cg = sci[0] + sci[1] + sci[2] + sci[3];
        double sum = sds[0] + sds[1] + sds[2] + sds[3];
        sum += (double)(Kp - cg) * (double)__uint_as_float(T);
        atomicAdd(&acc[2], sum);
    }
}

// ---------------- Kernel 6: final scalars -----------------------------------------------------
__global__ void k_final(const int* __restrict__ n_pos, const double* __restrict__ acc,
                        float* __restrict__ out) {
    if (threadIdx.x == 0) {
        int npt = 0;
        for (int b = 0; b < B; b++) npt += n_pos[b];
        double npf = (double)npt;
        float conf = (float)((acc[1] + acc[2]) / npf);
        float loc  = 10.0f * (float)(acc[0] / (npf * 4.0));
        out[0] = conf + loc;
        out[1] = conf;
        out[2] = loc;
    }
}

extern "C" void kernel_launch(void* const* d_in, const int* in_sizes, int n_in,
                              void* d_out, int out_size, void* d_ws, size_t ws_size,
                              hipStream_t stream) {
    const float* pred_cls = (const float*)d_in[0];
    const float* pred_loc = (const float*)d_in[1];
    const float* gt_boxes = (const float*)d_in[2];
    const int*   gt_labels = (const int*)d_in[3];
    const float* anchor   = (const float*)d_in[4];
    float* out = (float*)d_out;
    char* ws = (char*)d_ws;
    double* acc = (double*)(ws + OFF_ACC);
    int* n_pos = (int*)(ws + OFF_NPOS);
    int4* meta = (int4*)(ws + OFF_META);
    unsigned long long* obj_best = (unsigned long long*)(ws + OFF_OBJBEST);
    unsigned* hist = (unsigned*)(ws + OFF_HIST);
    float* ce_neg = (float*)(ws + OFF_CENEG);
    unsigned* list = (unsigned*)(ws + OFF_LIST);

    hipMemsetAsync(ws, 0, INIT_BYTES, stream);
    k_objmax<<<dim3(SCHUNK, B), 256, 0, stream>>>(gt_boxes, anchor, obj_best);
    k_main<<<dim3(NCHUNK, B), 256, 0, stream>>>(pred_cls, pred_loc, gt_boxes, gt_labels,
                                                anchor, obj_best, ce_neg, hist, n_pos, acc);
    k_sel2<<<B, 256, 0, stream>>>(hist, n_pos, meta);
    k_sel3<<<dim3((P + S3CHUNK - 1) / S3CHUNK, B), 256, 0, stream>>>(ce_neg, meta, list, acc);
    k_sel4<<<B, 256, 0, stream>>>(ce_neg, meta, list, acc);
    k_final<<<1, 64, 0, stream>>>(n_pos, acc, out);
}